// Round 1
// 1400.355 us; speedup vs baseline: 1.1766x; 1.1766x over previous
//
#include <hip/hip_runtime.h>
#include <cstdint>
#include <cstddef>

#define NB 512
#define NO 32
#define NR 2048
#define ND 256

typedef __attribute__((ext_vector_type(8))) __bf16 bf16x8;
typedef __attribute__((ext_vector_type(4))) float  f32x4;

// round-to-nearest-even fp32 -> bf16 (bit pattern in low 16)
__device__ __forceinline__ unsigned bf16_rne(float x) {
    unsigned u = __float_as_uint(x);
    return (u + 0x7FFFu + ((u >> 16) & 1u)) >> 16;
}

// split x = hi + lo (both bf16), exact residual
__device__ __forceinline__ void bf16_split(float x, unsigned& h, unsigned& l) {
    h = bf16_rne(x);
    float hf = __uint_as_float(h << 16);
    l = bf16_rne(x - hf);
}

// ------------------------------------------------------------------
// Kernel 1: S[b,o,r] = sum_d Q[b,o,d] * C[b,r,d] via split-bf16 MFMA.
// grid 4096 = (b:512) x (rtile:8, 256 r each); block 512 thr = 8 waves.
// Tile M=32 x N=256, K chunked by 64. LDS: bf16 hi/lo planes,
// XOR-swizzled rows (row stride 128B would be a 32-way bank conflict).
// Wave (wr=w>>2, wc=w&3) owns a 16x64 output tile: per 32-k step,
// 2 A-frag + 8 B-frag ds_read_b128 feed 12 mfma_f32_16x16x32_bf16
// (hi*hi + hi*lo + lo*hi; dropped lo*lo ~ 2^-18 relative).
// ------------------------------------------------------------------
__global__ __launch_bounds__(512, 4)
void k_scores(const float* __restrict__ Q, const float* __restrict__ C,
              float* __restrict__ S)
{
    __shared__ __align__(16) unsigned short Ahi[NO * 64];   // 4 KB
    __shared__ __align__(16) unsigned short Alo[NO * 64];   // 4 KB
    __shared__ __align__(16) unsigned short Bhi[256 * 64];  // 32 KB
    __shared__ __align__(16) unsigned short Blo[256 * 64];  // 32 KB

    const int t   = threadIdx.x;
    const int bid = blockIdx.x;
    const int b   = bid >> 3;
    const int rt  = bid & 7;

    const float* qb = Q + (size_t)b * NO * ND;
    const float* cb = C + (size_t)b * NR * ND + (size_t)rt * 256 * ND;

    // staging coords: B chunk 256x64 fp32 = 4096 float4, 8/thread
    //                 A chunk  32x64 fp32 =  512 float4, 1/thread
    const int a_row = t >> 4;   // 0..31
    const int a_k4  = t & 15;   // float4 slot in 64-float row chunk

    float4 pfB[8];
    float4 pfA;

    // ---- prologue: load chunk 0 into registers ----
#pragma unroll
    for (int i = 0; i < 8; ++i) {
        int f = t + 512 * i;
        int row = f >> 4, k4 = f & 15;
        pfB[i] = *(const float4*)(cb + (size_t)row * ND + k4 * 4);
    }
    pfA = *(const float4*)(qb + (size_t)a_row * ND + a_k4 * 4);

    // compute decomposition
    const int l   = t & 63;
    const int w   = t >> 6;
    const int wr  = w >> 2;          // 0..1 -> m0 = wr*16
    const int wc  = w & 3;           // 0..3 -> n0 = wc*64
    const int col = l & 15;          // operand row / D col
    const int kg  = l >> 4;          // 0..3  k-group
    const int key = (l & 7) << 3;    // XOR swizzle key (ushort units);
                                     // (arow&7)==(brow&7)==(l&7) here

    f32x4 acc[4];
#pragma unroll
    for (int nf = 0; nf < 4; ++nf) acc[nf] = f32x4{0.f, 0.f, 0.f, 0.f};

    const int arow = wr * 16 + col;
    const unsigned short* Ah = &Ahi[arow * 64];
    const unsigned short* Al = &Alo[arow * 64];

    for (int kc = 0; kc < 4; ++kc) {
        // ---- convert staged fp32 -> bf16 hi/lo, write swizzled LDS ----
#pragma unroll
        for (int i = 0; i < 8; ++i) {
            int f = t + 512 * i;
            int row = f >> 4, k4 = f & 15;
            int idx = row * 64 + ((k4 * 4) ^ ((row & 7) << 3));
            unsigned hx, lx, hy, ly, hz, lz, hw, lw;
            bf16_split(pfB[i].x, hx, lx);
            bf16_split(pfB[i].y, hy, ly);
            bf16_split(pfB[i].z, hz, lz);
            bf16_split(pfB[i].w, hw, lw);
            *(uint2*)&Bhi[idx] = make_uint2(hx | (hy << 16), hz | (hw << 16));
            *(uint2*)&Blo[idx] = make_uint2(lx | (ly << 16), lz | (lw << 16));
        }
        {
            int idx = a_row * 64 + ((a_k4 * 4) ^ ((a_row & 7) << 3));
            unsigned hx, lx, hy, ly, hz, lz, hw, lw;
            bf16_split(pfA.x, hx, lx);
            bf16_split(pfA.y, hy, ly);
            bf16_split(pfA.z, hz, lz);
            bf16_split(pfA.w, hw, lw);
            *(uint2*)&Ahi[idx] = make_uint2(hx | (hy << 16), hz | (hw << 16));
            *(uint2*)&Alo[idx] = make_uint2(lx | (ly << 16), lz | (lw << 16));
        }
        __syncthreads();   // LDS chunk ready

        // ---- prefetch next fp32 chunk under compute ----
        if (kc < 3) {
            const int k0 = (kc + 1) * 64;
#pragma unroll
            for (int i = 0; i < 8; ++i) {
                int f = t + 512 * i;
                int row = f >> 4, k4 = f & 15;
                pfB[i] = *(const float4*)(cb + (size_t)row * ND + k0 + k4 * 4);
            }
            pfA = *(const float4*)(qb + (size_t)a_row * ND + k0 + a_k4 * 4);
        }

        // ---- 2 k-steps of 32 ----
#pragma unroll
        for (int ks = 0; ks < 2; ++ks) {
            const int kidx = (ks * 32 + kg * 8) ^ key;   // 16B-aligned
            bf16x8 ah = *(const bf16x8*)&Ah[kidx];
            bf16x8 al = *(const bf16x8*)&Al[kidx];
#pragma unroll
            for (int nf = 0; nf < 4; ++nf) {
                int bidx = (wc * 64 + nf * 16 + col) * 64 + kidx;
                bf16x8 bh = *(const bf16x8*)&Bhi[bidx];
                bf16x8 bl = *(const bf16x8*)&Blo[bidx];
                acc[nf] = __builtin_amdgcn_mfma_f32_16x16x32_bf16(ah, bh, acc[nf], 0, 0, 0);
                acc[nf] = __builtin_amdgcn_mfma_f32_16x16x32_bf16(al, bh, acc[nf], 0, 0, 0);
                acc[nf] = __builtin_amdgcn_mfma_f32_16x16x32_bf16(ah, bl, acc[nf], 0, 0, 0);
            }
        }
        __syncthreads();   // all reads done before next chunk's writes
    }

    // ---- epilogue: D col = lane&15, row = (lane>>4)*4 + reg ----
    const int rb = kg * 4;
#pragma unroll
    for (int nf = 0; nf < 4; ++nf) {
#pragma unroll
        for (int j = 0; j < 4; ++j) {
            int o = wr * 16 + rb + j;
            int r = rt * 256 + wc * 64 + nf * 16 + col;
            S[((size_t)b * NO + o) * NR + r] = acc[nf][j];
        }
    }
}

// ------------------------------------------------------------------
// Kernel 2: in-place sparsemax over each row of 2048. (unchanged)
// One wave per row, Michelot fixed-point tau iteration.
// ------------------------------------------------------------------
__global__ __launch_bounds__(256)
void k_sparsemax(float* __restrict__ S)
{
    const int lane = threadIdx.x & 63;
    const int wv   = threadIdx.x >> 6;
    const size_t row = (size_t)blockIdx.x * 4 + wv;   // < 16384
    float4* p = (float4*)(S + row * NR);              // 512 float4 per row

    float4 v[8];
#pragma unroll
    for (int i = 0; i < 8; ++i) v[i] = p[lane + 64 * i];

    float m = -1e30f;
#pragma unroll
    for (int i = 0; i < 8; ++i)
        m = fmaxf(m, fmaxf(fmaxf(v[i].x, v[i].y), fmaxf(v[i].z, v[i].w)));
#pragma unroll
    for (int d = 1; d < 64; d <<= 1) m = fmaxf(m, __shfl_xor(m, d));

    float tau = m - 1.0f;
    for (int it = 0; it < 40; ++it) {
        float s = 0.f, c = 0.f;
#pragma unroll
        for (int i = 0; i < 8; ++i) {
            if (v[i].x > tau) { s += v[i].x; c += 1.f; }
            if (v[i].y > tau) { s += v[i].y; c += 1.f; }
            if (v[i].z > tau) { s += v[i].z; c += 1.f; }
            if (v[i].w > tau) { s += v[i].w; c += 1.f; }
        }
#pragma unroll
        for (int d = 1; d < 64; d <<= 1) {
            s += __shfl_xor(s, d);
            c += __shfl_xor(c, d);
        }
        float tn = (s - 1.0f) / c;   // c >= 1 always
        if (tn <= tau) break;        // fixed point -> exact tau
        tau = tn;
    }

#pragma unroll
    for (int i = 0; i < 8; ++i) {
        float4 wv4;
        wv4.x = fmaxf(v[i].x - tau, 0.f);
        wv4.y = fmaxf(v[i].y - tau, 0.f);
        wv4.z = fmaxf(v[i].z - tau, 0.f);
        wv4.w = fmaxf(v[i].w - tau, 0.f);
        p[lane + 64 * i] = wv4;
    }
}

extern "C" void kernel_launch(void* const* d_in, const int* in_sizes, int n_in,
                              void* d_out, int out_size, void* d_ws, size_t ws_size,
                              hipStream_t stream) {
    (void)in_sizes; (void)n_in; (void)d_ws; (void)ws_size; (void)out_size;
    const float* Q = (const float*)d_in[0];   // [512, 32, 256]
    const float* C = (const float*)d_in[1];   // [512, 2048, 256]
    float* out = (float*)d_out;               // [16384, 2048]

    hipLaunchKernelGGL(k_scores,    dim3(4096), dim3(512), 0, stream, Q, C, out);
    hipLaunchKernelGGL(k_sparsemax, dim3(4096), dim3(256), 0, stream, out);
}